// Round 2
// baseline (693.573 us; speedup 1.0000x reference)
//
#include <hip/hip_runtime.h>

#define N_NODES 50000
#define N_EDGES 800000
#define F_IN    256
#define H_DIM   64
#define C_DIM   16
#define PE_CNT  200000

// ---------------- CSR build ----------------

__global__ void hist_kernel(const int* __restrict__ dst, int* __restrict__ hist) {
    int e = blockIdx.x * blockDim.x + threadIdx.x;
    if (e < N_EDGES) atomicAdd(&hist[dst[e]], 1);
}

// Phase A: per-1024-chunk exclusive scan, write chunk totals.
__global__ __launch_bounds__(1024) void scan_block_kernel(const int* __restrict__ hist,
                                                          int* __restrict__ excl,
                                                          int* __restrict__ partials) {
    __shared__ int buf[1024];
    int i = blockIdx.x * 1024 + threadIdx.x;
    int v = (i < N_NODES) ? hist[i] : 0;
    buf[threadIdx.x] = v;
    __syncthreads();
    for (int off = 1; off < 1024; off <<= 1) {
        int t = (threadIdx.x >= off) ? buf[threadIdx.x - off] : 0;
        __syncthreads();
        buf[threadIdx.x] += t;
        __syncthreads();
    }
    int incl = buf[threadIdx.x];
    if (i < N_NODES) excl[i] = incl - v;
    if (threadIdx.x == 1023) partials[blockIdx.x] = incl;
}

// Phase B: scan the 49 chunk totals (single wave).
__global__ void scan_partials_kernel(int* __restrict__ partials) {
    int t = threadIdx.x;
    int orig = (t < 49) ? partials[t] : 0;
    int v = orig;
    for (int off = 1; off < 64; off <<= 1) {
        int u = __shfl_up(v, off, 64);
        if (t >= off) v += u;
    }
    if (t < 49) partials[t] = v - orig;   // exclusive
}

// Phase C: add chunk offsets, init cursor, compute dinv. Launch with N_NODES+1 coverage.
__global__ void scan_add_kernel(int* __restrict__ rowstart, const int* __restrict__ partials,
                                int* __restrict__ cursor, const int* __restrict__ hist,
                                float* __restrict__ dinv) {
    int i = blockIdx.x * blockDim.x + threadIdx.x;
    if (i < N_NODES) {
        int v = rowstart[i] + partials[i >> 10];
        rowstart[i] = v;
        cursor[i]   = v;
        dinv[i]     = rsqrtf((float)(hist[i] + 1));   // +1 self loop
    } else if (i == N_NODES) {
        rowstart[i] = N_EDGES;
    }
}

__global__ void scatter_kernel(const int* __restrict__ ei, int* __restrict__ cursor,
                               int* __restrict__ csr_src) {
    int e = blockIdx.x * blockDim.x + threadIdx.x;
    if (e < N_EDGES) {
        int s = ei[e];
        int d = ei[N_EDGES + e];
        int p = atomicAdd(&cursor[d], 1);
        csr_src[p] = s;
    }
}

// ---------------- GEMMs (f32 vector, W in LDS) ----------------

// x[50000,256] @ W[256,64]; 16 rows per block (3125 blocks exact).
__global__ __launch_bounds__(256) void gemm_k256_kernel(const float* __restrict__ x,
                                                        const float* __restrict__ W,
                                                        float* __restrict__ out) {
    __shared__ float Wl[F_IN * H_DIM];   // 64 KB
    const float4* W4 = (const float4*)W;
    float4* Wl4 = (float4*)Wl;
#pragma unroll
    for (int i = 0; i < 16; i++) Wl4[threadIdx.x + 256 * i] = W4[threadIdx.x + 256 * i];
    __syncthreads();
    int col  = threadIdx.x & 63;
    int rsub = threadIdx.x >> 6;
    int row0 = blockIdx.x * 16 + rsub;
    const float* x0 = x + (size_t)row0 * F_IN;
    float a0 = 0.f, a1 = 0.f, a2 = 0.f, a3 = 0.f;
#pragma unroll 8
    for (int k = 0; k < F_IN; k++) {
        float w = Wl[k * H_DIM + col];
        a0 += x0[k] * w;
        a1 += x0[4 * F_IN + k] * w;
        a2 += x0[8 * F_IN + k] * w;
        a3 += x0[12 * F_IN + k] * w;
    }
    out[(size_t)row0 * H_DIM + col]        = a0;
    out[(size_t)(row0 + 4) * H_DIM + col]  = a1;
    out[(size_t)(row0 + 8) * H_DIM + col]  = a2;
    out[(size_t)(row0 + 12) * H_DIM + col] = a3;
}

// x[50000,64] @ W[64,64]; 16 rows per block (3125 blocks exact).
__global__ __launch_bounds__(256) void gemm_k64_kernel(const float* __restrict__ x,
                                                       const float* __restrict__ W,
                                                       float* __restrict__ out) {
    __shared__ float Wl[H_DIM * H_DIM];  // 16 KB
    const float4* W4 = (const float4*)W;
    float4* Wl4 = (float4*)Wl;
#pragma unroll
    for (int i = 0; i < 4; i++) Wl4[threadIdx.x + 256 * i] = W4[threadIdx.x + 256 * i];
    __syncthreads();
    int col  = threadIdx.x & 63;
    int rsub = threadIdx.x >> 6;
    int row0 = blockIdx.x * 16 + rsub;
    const float* x0 = x + (size_t)row0 * H_DIM;
    float a0 = 0.f, a1 = 0.f, a2 = 0.f, a3 = 0.f;
#pragma unroll
    for (int k = 0; k < H_DIM; k++) {
        float w = Wl[k * H_DIM + col];
        a0 += x0[k] * w;
        a1 += x0[4 * H_DIM + k] * w;
        a2 += x0[8 * H_DIM + k] * w;
        a3 += x0[12 * H_DIM + k] * w;
    }
    out[(size_t)row0 * H_DIM + col]        = a0;
    out[(size_t)(row0 + 4) * H_DIM + col]  = a1;
    out[(size_t)(row0 + 8) * H_DIM + col]  = a2;
    out[(size_t)(row0 + 12) * H_DIM + col] = a3;
}

// x[50000,64] @ W[64,16]; 16 rows per block (3125 blocks exact).
__global__ __launch_bounds__(256) void gemm_head_kernel(const float* __restrict__ x,
                                                        const float* __restrict__ W,
                                                        float* __restrict__ out) {
    __shared__ float Wl[H_DIM * C_DIM];  // 4 KB
    ((float4*)Wl)[threadIdx.x] = ((const float4*)W)[threadIdx.x];
    __syncthreads();
    int col  = threadIdx.x & 15;
    int rsub = threadIdx.x >> 4;
    int row  = blockIdx.x * 16 + rsub;
    const float* x0 = x + (size_t)row * H_DIM;
    float acc = 0.f;
#pragma unroll
    for (int k = 0; k < H_DIM; k++) acc += x0[k] * Wl[k * C_DIM + col];
    out[(size_t)row * C_DIM + col] = acc;
}

// ---------------- GCN aggregation (CSR gather, no atomics) ----------------

// One wave per node, lane = feature (H=64).
__global__ __launch_bounds__(256) void agg64_kernel(const float* __restrict__ h,
                                                    const int* __restrict__ rowstart,
                                                    const int* __restrict__ csr_src,
                                                    const float* __restrict__ dinv,
                                                    const float* __restrict__ b,
                                                    float* __restrict__ out, int relu) {
    int lane = threadIdx.x & 63;
    int node = blockIdx.x * 4 + (threadIdx.x >> 6);
    if (node >= N_NODES) return;
    float dn  = dinv[node];
    float acc = dn * h[(size_t)node * H_DIM + lane];   // self loop (pre-dn)
    int s0 = rowstart[node], s1 = rowstart[node + 1];
    for (int j = s0; j < s1; j++) {
        int s = csr_src[j];
        acc += dinv[s] * h[(size_t)s * H_DIM + lane];
    }
    float v = dn * acc + b[lane];
    if (relu) v = fmaxf(v, 0.f);
    out[(size_t)node * H_DIM + lane] = v;
}

// 16-lane group per node (C=16); optional fused log-softmax over the group.
template <int DO_LSM>
__global__ __launch_bounds__(256) void agg16_kernel(const float* __restrict__ h,
                                                    const int* __restrict__ rowstart,
                                                    const int* __restrict__ csr_src,
                                                    const float* __restrict__ dinv,
                                                    const float* __restrict__ b,
                                                    float* __restrict__ out) {
    int lane = threadIdx.x & 15;
    int node = blockIdx.x * 16 + (threadIdx.x >> 4);
    if (node >= N_NODES) return;
    float dn  = dinv[node];
    float acc = dn * h[(size_t)node * C_DIM + lane];
    int s0 = rowstart[node], s1 = rowstart[node + 1];
    for (int j = s0; j < s1; j++) {
        int s = csr_src[j];
        acc += dinv[s] * h[(size_t)s * C_DIM + lane];
    }
    float v = dn * acc + b[lane];
    if (DO_LSM) {
        float m = v;
#pragma unroll
        for (int off = 1; off < 16; off <<= 1) m = fmaxf(m, __shfl_xor(m, off, 64));
        float e = __expf(v - m);
        float s = e;
#pragma unroll
        for (int off = 1; off < 16; off <<= 1) s += __shfl_xor(s, off, 64);
        v = (v - m) - __logf(s);
    }
    out[(size_t)node * C_DIM + lane] = v;
}

// ---------------- edge dot decoder ----------------

// 16 lanes per edge, float4 loads (64 floats = 16 lanes x float4).
__global__ __launch_bounds__(256) void edge_dot_kernel(const int* __restrict__ pos,
                                                       const int* __restrict__ neg,
                                                       const float* __restrict__ x,
                                                       float* __restrict__ res) {
    int e = blockIdx.x * 16 + (threadIdx.x >> 4);
    int lane = threadIdx.x & 15;
    int a, b;
    if (e < PE_CNT) {
        a = pos[e];
        b = pos[PE_CNT + e];
    } else {
        int e2 = e - PE_CNT;
        a = neg[e2];
        b = neg[PE_CNT + e2];
    }
    float4 xa = ((const float4*)(x + (size_t)a * H_DIM))[lane];
    float4 xb = ((const float4*)(x + (size_t)b * H_DIM))[lane];
    float acc = xa.x * xb.x + xa.y * xb.y + xa.z * xb.z + xa.w * xb.w;
#pragma unroll
    for (int off = 1; off < 16; off <<= 1) acc += __shfl_xor(acc, off, 64);
    if (lane == 0) res[e] = acc;
}

// ---------------- launch ----------------

extern "C" void kernel_launch(void* const* d_in, const int* in_sizes, int n_in,
                              void* d_out, int out_size, void* d_ws, size_t ws_size,
                              hipStream_t stream) {
    const float* input = (const float*)d_in[0];
    // d_in[1] = glove = identity -> x @ glove == x, skipped exactly.
    const float* W1 = (const float*)d_in[2];
    const float* b1 = (const float*)d_in[3];
    const float* W2 = (const float*)d_in[4];
    const float* b2 = (const float*)d_in[5];
    const float* W3 = (const float*)d_in[6];
    const float* b3 = (const float*)d_in[7];
    const float* Wa = (const float*)d_in[8];
    const float* ba = (const float*)d_in[9];
    const float* Wk = (const float*)d_in[10];
    const float* bk = (const float*)d_in[11];
    const int* ei  = (const int*)d_in[12];
    const int* pos = (const int*)d_in[13];
    const int* neg = (const int*)d_in[14];

    char* ws = (char*)d_ws;
    int*   hist     = (int*)(ws + 0);               // 200000 B
    int*   rowstart = (int*)(ws + 200704);          // 200004 B
    int*   cursor   = (int*)(ws + 401408);          // 200000 B
    float* dinv     = (float*)(ws + 602112);        // 200000 B
    int*   partials = (int*)(ws + 802816);          // 196 B
    int*   csr      = (int*)(ws + 803840);          // 3.2 MB
    float* bufA     = (float*)(ws + 4003840ULL);    // 12.8 MB
    float* bufB     = (float*)(ws + 16803840ULL);   // 12.8 MB  (end ~29.6 MB)

    float* out  = (float*)d_out;
    float* res  = out;                  // 400000
    float* lsm  = out + 400000;         // 800000
    float* att  = out + 1200000;        // 800000
    float* feat = out + 2000000;        // 3200000

    // CSR build
    hipMemsetAsync(hist, 0, N_NODES * sizeof(int), stream);
    hist_kernel<<<(N_EDGES + 255) / 256, 256, 0, stream>>>(ei + N_EDGES, hist);
    scan_block_kernel<<<49, 1024, 0, stream>>>(hist, rowstart, partials);
    scan_partials_kernel<<<1, 64, 0, stream>>>(partials);
    scan_add_kernel<<<(N_NODES + 256) / 256, 256, 0, stream>>>(rowstart, partials, cursor, hist, dinv);
    scatter_kernel<<<(N_EDGES + 255) / 256, 256, 0, stream>>>(ei, cursor, csr);

    // layer 1: h1 = x @ W1 ; x1 = relu(agg(h1) + b1)
    gemm_k256_kernel<<<3125, 256, 0, stream>>>(input, W1, bufA);
    agg64_kernel<<<12500, 256, 0, stream>>>(bufA, rowstart, csr, dinv, b1, bufB, 1);
    // layer 2
    gemm_k64_kernel<<<3125, 256, 0, stream>>>(bufB, W2, bufA);
    agg64_kernel<<<12500, 256, 0, stream>>>(bufA, rowstart, csr, dinv, b2, bufB, 0);
    // layer 3 -> feat (directly into d_out)
    gemm_k64_kernel<<<3125, 256, 0, stream>>>(bufB, W3, bufA);
    agg64_kernel<<<12500, 256, 0, stream>>>(bufA, rowstart, csr, dinv, b3, feat, 0);

    // attr head (+ fused log-softmax)
    gemm_head_kernel<<<3125, 256, 0, stream>>>(feat, Wa, bufA);
    agg16_kernel<1><<<3125, 256, 0, stream>>>(bufA, rowstart, csr, dinv, ba, lsm);
    // att head (grad_reverse is identity in forward)
    gemm_head_kernel<<<3125, 256, 0, stream>>>(feat, Wk, bufA);
    agg16_kernel<0><<<3125, 256, 0, stream>>>(bufA, rowstart, csr, dinv, bk, att);

    // edge dot products
    edge_dot_kernel<<<25000, 256, 0, stream>>>(pos, neg, feat, res);
}

// Round 3
// 542.926 us; speedup vs baseline: 1.2775x; 1.2775x over previous
//
#include <hip/hip_runtime.h>
#include <hip/hip_bf16.h>

#define N_NODES 50000
#define N_EDGES 800000
#define F_IN    256
#define H_DIM   64
#define C_DIM   16
#define PE_CNT  200000

typedef __hip_bfloat16 bf16;

__device__ __forceinline__ float b2f(bf16 v) { return __bfloat162float(v); }
__device__ __forceinline__ bf16  f2b(float v) { return __float2bfloat16(v); }

// ---------------- CSR build ----------------

// hist over dst; block 0 additionally packs Wh[64][32] = [Wa | Wk] for the head kernel.
__global__ void hist_build_kernel(const int* __restrict__ dst, int* __restrict__ hist,
                                  const float* __restrict__ Wa, const float* __restrict__ Wk,
                                  float* __restrict__ Wh) {
    int e = blockIdx.x * blockDim.x + threadIdx.x;
    if (e < N_EDGES) atomicAdd(&hist[dst[e]], 1);
    if (blockIdx.x == 0) {
        for (int idx = threadIdx.x; idx < H_DIM * 32; idx += 256) {
            int f = idx >> 5, c = idx & 31;
            Wh[idx] = (c < C_DIM) ? Wa[f * C_DIM + c] : Wk[f * C_DIM + (c - C_DIM)];
        }
    }
}

__global__ __launch_bounds__(1024) void scan_block_kernel(const int* __restrict__ hist,
                                                          int* __restrict__ excl,
                                                          int* __restrict__ partials) {
    __shared__ int buf[1024];
    int i = blockIdx.x * 1024 + threadIdx.x;
    int v = (i < N_NODES) ? hist[i] : 0;
    buf[threadIdx.x] = v;
    __syncthreads();
    for (int off = 1; off < 1024; off <<= 1) {
        int t = (threadIdx.x >= off) ? buf[threadIdx.x - off] : 0;
        __syncthreads();
        buf[threadIdx.x] += t;
        __syncthreads();
    }
    int incl = buf[threadIdx.x];
    if (i < N_NODES) excl[i] = incl - v;
    if (threadIdx.x == 1023) partials[blockIdx.x] = incl;
}

__global__ void scan_partials_kernel(int* __restrict__ partials) {
    int t = threadIdx.x;
    int orig = (t < 49) ? partials[t] : 0;
    int v = orig;
    for (int off = 1; off < 64; off <<= 1) {
        int u = __shfl_up(v, off, 64);
        if (t >= off) v += u;
    }
    if (t < 49) partials[t] = v - orig;
}

__global__ void scan_add_kernel(int* __restrict__ rowstart, const int* __restrict__ partials,
                                int* __restrict__ cursor, const int* __restrict__ hist,
                                float* __restrict__ dinv) {
    int i = blockIdx.x * blockDim.x + threadIdx.x;
    if (i < N_NODES) {
        int v = rowstart[i] + partials[i >> 10];
        rowstart[i] = v;
        cursor[i]   = v;
        dinv[i]     = rsqrtf((float)(hist[i] + 1));
    } else if (i == N_NODES) {
        rowstart[i] = N_EDGES;
    }
}

// csr2[p] = (src, dinv[src]) — one 8B record per edge.
__global__ void scatter_kernel(const int* __restrict__ ei, int* __restrict__ cursor,
                               const float* __restrict__ dinv, int2* __restrict__ csr2) {
    int e = blockIdx.x * blockDim.x + threadIdx.x;
    if (e < N_EDGES) {
        int s = ei[e];
        int d = ei[N_EDGES + e];
        int p = atomicAdd(&cursor[d], 1);
        csr2[p] = make_int2(s, __float_as_int(dinv[s]));
    }
}

// ---------------- layer-1 GEMM: x[50000,256] @ W1[256,64] -> h1 (bf16) ----------------
// One wave = 16 rows; lane = col. x-row loads are wave-uniform (readfirstlane) -> s_load
// through the scalar cache; W rows stream coalesced from L1/L2. No LDS -> high occupancy.
__global__ __launch_bounds__(256) void gemm_k256_kernel(const float* __restrict__ x,
                                                        const float* __restrict__ W,
                                                        bf16* __restrict__ h1) {
    int col = threadIdx.x & 63;
    int wid = __builtin_amdgcn_readfirstlane(threadIdx.x >> 6);
    int row0 = blockIdx.x * 64 + wid * 16;
    if (row0 >= N_NODES) return;   // tail: whole wave OOB or whole wave valid
    const float* xp = x + (size_t)row0 * F_IN;
    float acc[16];
#pragma unroll
    for (int i = 0; i < 16; i++) acc[i] = 0.f;
    for (int k = 0; k < F_IN; k += 4) {
        float w0 = W[(k + 0) * H_DIM + col];
        float w1 = W[(k + 1) * H_DIM + col];
        float w2 = W[(k + 2) * H_DIM + col];
        float w3 = W[(k + 3) * H_DIM + col];
#pragma unroll
        for (int i = 0; i < 16; i++) {
            acc[i] += xp[i * F_IN + k + 0] * w0;
            acc[i] += xp[i * F_IN + k + 1] * w1;
            acc[i] += xp[i * F_IN + k + 2] * w2;
            acc[i] += xp[i * F_IN + k + 3] * w3;
        }
    }
#pragma unroll
    for (int i = 0; i < 16; i++)
        h1[(size_t)(row0 + i) * H_DIM + col] = f2b(acc[i]);
}

// ---------------- fused agg + next-layer GEMM ----------------
// Per node (1 wave, lane=feature): v = relu?(dn*(self + sum w_j h_j) + bagg)
// then h_next[node] = v @ W (64x64) via wave shuffles; store bf16.
template <int RELU>
__global__ __launch_bounds__(256) void agg_gemm_kernel(const bf16* __restrict__ h,
                                                       const int* __restrict__ rowstart,
                                                       const int2* __restrict__ csr2,
                                                       const float* __restrict__ dinv,
                                                       const float* __restrict__ bagg,
                                                       const float* __restrict__ W,
                                                       bf16* __restrict__ hnext) {
    int lane = threadIdx.x & 63;
    int node = blockIdx.x * 4 + __builtin_amdgcn_readfirstlane(threadIdx.x >> 6);
    float dn = dinv[node];
    int s0 = rowstart[node], s1 = rowstart[node + 1];
    float acc0 = dn * b2f(h[(size_t)node * H_DIM + lane]);   // self loop
    float acc1 = 0.f;
    int j = s0;
    for (; j + 1 < s1; j += 2) {
        int2 e0 = csr2[j], e1 = csr2[j + 1];
        acc0 += __int_as_float(e0.y) * b2f(h[(size_t)e0.x * H_DIM + lane]);
        acc1 += __int_as_float(e1.y) * b2f(h[(size_t)e1.x * H_DIM + lane]);
    }
    if (j < s1) {
        int2 e0 = csr2[j];
        acc0 += __int_as_float(e0.y) * b2f(h[(size_t)e0.x * H_DIM + lane]);
    }
    float v = dn * (acc0 + acc1) + bagg[lane];
    if (RELU) v = fmaxf(v, 0.f);
    float o = 0.f;
#pragma unroll
    for (int f = 0; f < H_DIM; f++) {
        float vf = __shfl(v, f, 64);
        o += vf * W[f * H_DIM + lane];
    }
    hnext[(size_t)node * H_DIM + lane] = f2b(o);
}

// ---------------- layer-3 agg -> feat (f32 out) + featb (bf16 for gathers) ----------------
__global__ __launch_bounds__(256) void agg_out_kernel(const bf16* __restrict__ h,
                                                      const int* __restrict__ rowstart,
                                                      const int2* __restrict__ csr2,
                                                      const float* __restrict__ dinv,
                                                      const float* __restrict__ b3,
                                                      float* __restrict__ feat,
                                                      bf16* __restrict__ featb) {
    int lane = threadIdx.x & 63;
    int node = blockIdx.x * 4 + __builtin_amdgcn_readfirstlane(threadIdx.x >> 6);
    float dn = dinv[node];
    int s0 = rowstart[node], s1 = rowstart[node + 1];
    float acc0 = dn * b2f(h[(size_t)node * H_DIM + lane]);
    float acc1 = 0.f;
    int j = s0;
    for (; j + 1 < s1; j += 2) {
        int2 e0 = csr2[j], e1 = csr2[j + 1];
        acc0 += __int_as_float(e0.y) * b2f(h[(size_t)e0.x * H_DIM + lane]);
        acc1 += __int_as_float(e1.y) * b2f(h[(size_t)e1.x * H_DIM + lane]);
    }
    if (j < s1) {
        int2 e0 = csr2[j];
        acc0 += __int_as_float(e0.y) * b2f(h[(size_t)e0.x * H_DIM + lane]);
    }
    float v = dn * (acc0 + acc1) + b3[lane];
    feat[(size_t)node * H_DIM + lane]  = v;
    featb[(size_t)node * H_DIM + lane] = f2b(v);
}

// ---------------- heads: y = A*feat (no bias); attr=y@Wa+ba (log-softmax), att=y@Wk+bk ----
// Dual-head shuffle GEMM against packed Wh[64][32]; lanes 0-15 -> lsm, 16-31 -> att.
__global__ __launch_bounds__(256) void head_kernel(const bf16* __restrict__ featb,
                                                   const int* __restrict__ rowstart,
                                                   const int2* __restrict__ csr2,
                                                   const float* __restrict__ dinv,
                                                   const float* __restrict__ Wh,
                                                   const float* __restrict__ ba,
                                                   const float* __restrict__ bk,
                                                   float* __restrict__ lsm,
                                                   float* __restrict__ att) {
    int lane = threadIdx.x & 63;
    int node = blockIdx.x * 4 + __builtin_amdgcn_readfirstlane(threadIdx.x >> 6);
    float dn = dinv[node];
    int s0 = rowstart[node], s1 = rowstart[node + 1];
    float acc0 = dn * b2f(featb[(size_t)node * H_DIM + lane]);
    float acc1 = 0.f;
    int j = s0;
    for (; j + 1 < s1; j += 2) {
        int2 e0 = csr2[j], e1 = csr2[j + 1];
        acc0 += __int_as_float(e0.y) * b2f(featb[(size_t)e0.x * H_DIM + lane]);
        acc1 += __int_as_float(e1.y) * b2f(featb[(size_t)e1.x * H_DIM + lane]);
    }
    if (j < s1) {
        int2 e0 = csr2[j];
        acc0 += __int_as_float(e0.y) * b2f(featb[(size_t)e0.x * H_DIM + lane]);
    }
    float y = dn * (acc0 + acc1);     // no bias on y

    // partial[l] = sum_{i=0..31} y[fbase+i] * Wh[fbase+i][c32]
    int c32 = lane & 31;
    int fbase = lane & 32;
    float part = 0.f;
#pragma unroll
    for (int i = 0; i < 32; i++) {
        float yf = __shfl(y, fbase + i, 64);
        part += yf * Wh[(fbase + i) * 32 + c32];
    }
    float full = part + __shfl(part, lane ^ 32, 64);   // valid for lanes 0..31
    if (lane < 32) {
        float bias = (lane < C_DIM) ? ba[lane] : bk[lane - C_DIM];
        float hv = full + bias;
        if (lane < C_DIM) {
            float m = hv;
#pragma unroll
            for (int off = 1; off < 16; off <<= 1) m = fmaxf(m, __shfl_xor(m, off, 64));
            float e = __expf(hv - m);
            float sum = e;
#pragma unroll
            for (int off = 1; off < 16; off <<= 1) sum += __shfl_xor(sum, off, 64);
            lsm[(size_t)node * C_DIM + lane] = (hv - m) - __logf(sum);
        } else {
            att[(size_t)node * C_DIM + (lane - C_DIM)] = hv;
        }
    }
}

// ---------------- edge dot on bf16 feat ----------------
__global__ __launch_bounds__(256) void edge_dot_kernel(const int* __restrict__ pos,
                                                       const int* __restrict__ neg,
                                                       const bf16* __restrict__ xb,
                                                       float* __restrict__ res) {
    int e = blockIdx.x * 16 + (threadIdx.x >> 4);
    int lane = threadIdx.x & 15;
    int a, b;
    if (e < PE_CNT) {
        a = pos[e];
        b = pos[PE_CNT + e];
    } else {
        int e2 = e - PE_CNT;
        a = neg[e2];
        b = neg[PE_CNT + e2];
    }
    uint2 ua = ((const uint2*)(xb + (size_t)a * H_DIM))[lane];
    uint2 ub = ((const uint2*)(xb + (size_t)b * H_DIM))[lane];
    float a0 = __uint_as_float(ua.x << 16), a1 = __uint_as_float(ua.x & 0xffff0000u);
    float a2 = __uint_as_float(ua.y << 16), a3 = __uint_as_float(ua.y & 0xffff0000u);
    float b0 = __uint_as_float(ub.x << 16), b1 = __uint_as_float(ub.x & 0xffff0000u);
    float b2 = __uint_as_float(ub.y << 16), b3 = __uint_as_float(ub.y & 0xffff0000u);
    float acc = a0 * b0 + a1 * b1 + a2 * b2 + a3 * b3;
#pragma unroll
    for (int off = 1; off < 16; off <<= 1) acc += __shfl_xor(acc, off, 64);
    if (lane == 0) res[e] = acc;
}

// ---------------- launch ----------------

extern "C" void kernel_launch(void* const* d_in, const int* in_sizes, int n_in,
                              void* d_out, int out_size, void* d_ws, size_t ws_size,
                              hipStream_t stream) {
    const float* input = (const float*)d_in[0];
    // d_in[1] = glove = identity: x @ glove == x, skipped exactly.
    const float* W1 = (const float*)d_in[2];
    const float* b1 = (const float*)d_in[3];
    const float* W2 = (const float*)d_in[4];
    const float* b2 = (const float*)d_in[5];
    const float* W3 = (const float*)d_in[6];
    const float* b3 = (const float*)d_in[7];
    const float* Wa = (const float*)d_in[8];
    const float* ba = (const float*)d_in[9];
    const float* Wk = (const float*)d_in[10];
    const float* bk = (const float*)d_in[11];
    const int* ei  = (const int*)d_in[12];
    const int* pos = (const int*)d_in[13];
    const int* neg = (const int*)d_in[14];

    char* ws = (char*)d_ws;
    int*   hist     = (int*)(ws + 0);                 // 200000
    int*   rowstart = (int*)(ws + 200704);            // 200004
    int*   cursor   = (int*)(ws + 401408);            // 200000
    float* dinv     = (float*)(ws + 602112);          // 200000
    int*   partials = (int*)(ws + 802816);            // 256
    float* Wh       = (float*)(ws + 803072);          // 8192
    int2*  csr2     = (int2*)(ws + 811264);           // 6.4 MB
    bf16*  bufA     = (bf16*)(ws + 7211264ULL);       // 6.4 MB
    bf16*  bufB     = (bf16*)(ws + 13611264ULL);      // 6.4 MB (end ~20 MB)

    float* out  = (float*)d_out;
    float* res  = out;                  // 400000
    float* lsm  = out + 400000;         // 800000
    float* att  = out + 1200000;        // 800000
    float* feat = out + 2000000;        // 3200000

    // CSR build (+ Wh pack piggybacked on block 0 of hist)
    hipMemsetAsync(hist, 0, N_NODES * sizeof(int), stream);
    hist_build_kernel<<<(N_EDGES + 255) / 256, 256, 0, stream>>>(ei + N_EDGES, hist, Wa, Wk, Wh);
    scan_block_kernel<<<49, 1024, 0, stream>>>(hist, rowstart, partials);
    scan_partials_kernel<<<1, 64, 0, stream>>>(partials);
    scan_add_kernel<<<196, 256, 0, stream>>>(rowstart, partials, cursor, hist, dinv);
    scatter_kernel<<<(N_EDGES + 255) / 256, 256, 0, stream>>>(ei, cursor, dinv, csr2);

    // layer 1 GEMM (f32 in, bf16 out)
    gemm_k256_kernel<<<782, 256, 0, stream>>>(input, W1, bufA);
    // layer 1 agg (+b1, relu) fused with layer-2 GEMM
    agg_gemm_kernel<1><<<12500, 256, 0, stream>>>(bufA, rowstart, csr2, dinv, b1, W2, bufB);
    // layer 2 agg (+b2) fused with layer-3 GEMM
    agg_gemm_kernel<0><<<12500, 256, 0, stream>>>(bufB, rowstart, csr2, dinv, b2, W3, bufA);
    // layer 3 agg (+b3) -> feat (f32) + featb (bf16)
    agg_out_kernel<<<12500, 256, 0, stream>>>(bufA, rowstart, csr2, dinv, b3, feat, bufB);
    // heads: y = A*feat; attr=y@Wa+ba (log-softmax) ; att=y@Wk+bk
    head_kernel<<<12500, 256, 0, stream>>>(bufB, rowstart, csr2, dinv, Wh, ba, bk, lsm, att);
    // edge dot on bf16 feat
    edge_dot_kernel<<<25000, 256, 0, stream>>>(pos, neg, bufB, res);
}

// Round 4
// 436.962 us; speedup vs baseline: 1.5873x; 1.2425x over previous
//
#include <hip/hip_runtime.h>
#include <hip/hip_bf16.h>

#define N_NODES 50000
#define N_EDGES 800000
#define F_IN    256
#define H_DIM   64
#define C_DIM   16
#define PE_CNT  200000

typedef __hip_bfloat16 bf16;

__device__ __forceinline__ float b2f(bf16 v) { return __bfloat162float(v); }
__device__ __forceinline__ bf16  f2b(float v) { return __float2bfloat16(v); }

// ---------------- CSR build ----------------

// hist over dst; block 0 additionally packs Wh[64][32] = [Wa | Wk] for the head kernel.
__global__ void hist_build_kernel(const int* __restrict__ dst, int* __restrict__ hist,
                                  const float* __restrict__ Wa, const float* __restrict__ Wk,
                                  float* __restrict__ Wh) {
    int e = blockIdx.x * blockDim.x + threadIdx.x;
    if (e < N_EDGES) atomicAdd(&hist[dst[e]], 1);
    if (blockIdx.x == 0) {
        for (int idx = threadIdx.x; idx < H_DIM * 32; idx += 256) {
            int f = idx >> 5, c = idx & 31;
            Wh[idx] = (c < C_DIM) ? Wa[f * C_DIM + c] : Wk[f * C_DIM + (c - C_DIM)];
        }
    }
}

__global__ __launch_bounds__(1024) void scan_block_kernel(const int* __restrict__ hist,
                                                          int* __restrict__ excl,
                                                          int* __restrict__ partials) {
    __shared__ int buf[1024];
    int i = blockIdx.x * 1024 + threadIdx.x;
    int v = (i < N_NODES) ? hist[i] : 0;
    buf[threadIdx.x] = v;
    __syncthreads();
    for (int off = 1; off < 1024; off <<= 1) {
        int t = (threadIdx.x >= off) ? buf[threadIdx.x - off] : 0;
        __syncthreads();
        buf[threadIdx.x] += t;
        __syncthreads();
    }
    int incl = buf[threadIdx.x];
    if (i < N_NODES) excl[i] = incl - v;
    if (threadIdx.x == 1023) partials[blockIdx.x] = incl;
}

__global__ void scan_partials_kernel(int* __restrict__ partials) {
    int t = threadIdx.x;
    int orig = (t < 49) ? partials[t] : 0;
    int v = orig;
    for (int off = 1; off < 64; off <<= 1) {
        int u = __shfl_up(v, off, 64);
        if (t >= off) v += u;
    }
    if (t < 49) partials[t] = v - orig;
}

__global__ void scan_add_kernel(int* __restrict__ rowstart, const int* __restrict__ partials,
                                int* __restrict__ cursor, const int* __restrict__ hist,
                                float* __restrict__ dinv) {
    int i = blockIdx.x * blockDim.x + threadIdx.x;
    if (i < N_NODES) {
        int v = rowstart[i] + partials[i >> 10];
        rowstart[i] = v;
        cursor[i]   = v;
        dinv[i]     = rsqrtf((float)(hist[i] + 1));
    } else if (i == N_NODES) {
        rowstart[i] = N_EDGES;
    }
}

// csr2[p] = (src, dinv[src]) — one 8B record per edge.
__global__ void scatter_kernel(const int* __restrict__ ei, int* __restrict__ cursor,
                               const float* __restrict__ dinv, int2* __restrict__ csr2) {
    int e = blockIdx.x * blockDim.x + threadIdx.x;
    if (e < N_EDGES) {
        int s = ei[e];
        int d = ei[N_EDGES + e];
        int p = atomicAdd(&cursor[d], 1);
        csr2[p] = make_int2(s, __float_as_int(dinv[s]));
    }
}

// ---------------- layer-1 GEMM: x[50000,256] @ W1[256,64] -> h1 (bf16) ----------------
// LDS-tiled f32 GEMM. 32 rows/block, K chunked by 64. xs staged coalesced (float4),
// ws chunk staged coalesced. Compute: thread = (col, 8 rows); x values are broadcast
// ds_read_b128 (same-address, conflict-free), w stride-1 b32. LDS 24.5 KB -> 6 blocks/CU.
#define G_ROWS 32
#define G_KCH  64
#define XS_LD  68   // 64 + 4 pad, keeps rows 16B-aligned (68*4=272=17*16)

__global__ __launch_bounds__(256) void gemm_k256_kernel(const float* __restrict__ x,
                                                        const float* __restrict__ W,
                                                        bf16* __restrict__ h1) {
    __shared__ float xs[G_ROWS * XS_LD];   // 8704 B
    __shared__ float ws[G_KCH * H_DIM];    // 16384 B
    int t = threadIdx.x;
    int row0 = blockIdx.x * G_ROWS;
    int col = t & 63;
    int wv  = t >> 6;

    float acc[8];
#pragma unroll
    for (int i = 0; i < 8; i++) acc[i] = 0.f;

    for (int c = 0; c < F_IN / G_KCH; c++) {
        int k0 = c * G_KCH;
        // stage W chunk: 64x64 floats, coalesced float4, linear.
        {
            const float4* Wg = (const float4*)(W + k0 * H_DIM);
            float4* wl = (float4*)ws;
#pragma unroll
            for (int i = 0; i < 4; i++) wl[t + 256 * i] = Wg[t + 256 * i];
        }
        // stage x chunk: 32 rows x 64 k. 8 threads/row, 8 floats (2 float4) each.
        {
            int r = t >> 3;
            int jj = (t & 7) * 8;
            int row = row0 + r;
            float4 v0 = make_float4(0.f, 0.f, 0.f, 0.f), v1 = v0;
            if (row < N_NODES) {
                const float4* xg = (const float4*)(x + (size_t)row * F_IN + k0 + jj);
                v0 = xg[0];
                v1 = xg[1];
            }
            float4* xl = (float4*)&xs[r * XS_LD + jj];
            xl[0] = v0;
            xl[1] = v1;
        }
        __syncthreads();
        // compute
#pragma unroll 4
        for (int kk = 0; kk < G_KCH; kk += 4) {
            float w0 = ws[(kk + 0) * H_DIM + col];
            float w1 = ws[(kk + 1) * H_DIM + col];
            float w2 = ws[(kk + 2) * H_DIM + col];
            float w3 = ws[(kk + 3) * H_DIM + col];
#pragma unroll
            for (int i = 0; i < 8; i++) {
                float4 xv = *(const float4*)&xs[(wv * 8 + i) * XS_LD + kk];
                acc[i] += xv.x * w0 + xv.y * w1 + xv.z * w2 + xv.w * w3;
            }
        }
        __syncthreads();
    }
#pragma unroll
    for (int i = 0; i < 8; i++) {
        int row = row0 + wv * 8 + i;
        if (row < N_NODES) h1[(size_t)row * H_DIM + col] = f2b(acc[i]);
    }
}

// ---------------- fused agg + next-layer GEMM ----------------
// Per node (1 wave, lane=feature): v = relu?(dn*(self + sum w_j h_j) + bagg)
// then h_next[node] = v @ W (64x64) via wave shuffles; store bf16.
template <int RELU>
__global__ __launch_bounds__(256) void agg_gemm_kernel(const bf16* __restrict__ h,
                                                       const int* __restrict__ rowstart,
                                                       const int2* __restrict__ csr2,
                                                       const float* __restrict__ dinv,
                                                       const float* __restrict__ bagg,
                                                       const float* __restrict__ W,
                                                       bf16* __restrict__ hnext) {
    int lane = threadIdx.x & 63;
    int node = blockIdx.x * 4 + __builtin_amdgcn_readfirstlane(threadIdx.x >> 6);
    float dn = dinv[node];
    int s0 = rowstart[node], s1 = rowstart[node + 1];
    float acc0 = dn * b2f(h[(size_t)node * H_DIM + lane]);   // self loop
    float acc1 = 0.f;
    int j = s0;
    for (; j + 1 < s1; j += 2) {
        int2 e0 = csr2[j], e1 = csr2[j + 1];
        acc0 += __int_as_float(e0.y) * b2f(h[(size_t)e0.x * H_DIM + lane]);
        acc1 += __int_as_float(e1.y) * b2f(h[(size_t)e1.x * H_DIM + lane]);
    }
    if (j < s1) {
        int2 e0 = csr2[j];
        acc0 += __int_as_float(e0.y) * b2f(h[(size_t)e0.x * H_DIM + lane]);
    }
    float v = dn * (acc0 + acc1) + bagg[lane];
    if (RELU) v = fmaxf(v, 0.f);
    float o = 0.f;
#pragma unroll
    for (int f = 0; f < H_DIM; f++) {
        float vf = __shfl(v, f, 64);
        o += vf * W[f * H_DIM + lane];
    }
    hnext[(size_t)node * H_DIM + lane] = f2b(o);
}

// ---------------- layer-3 agg -> feat (f32 out) + featb (bf16 for gathers) ----------------
__global__ __launch_bounds__(256) void agg_out_kernel(const bf16* __restrict__ h,
                                                      const int* __restrict__ rowstart,
                                                      const int2* __restrict__ csr2,
                                                      const float* __restrict__ dinv,
                                                      const float* __restrict__ b3,
                                                      float* __restrict__ feat,
                                                      bf16* __restrict__ featb) {
    int lane = threadIdx.x & 63;
    int node = blockIdx.x * 4 + __builtin_amdgcn_readfirstlane(threadIdx.x >> 6);
    float dn = dinv[node];
    int s0 = rowstart[node], s1 = rowstart[node + 1];
    float acc0 = dn * b2f(h[(size_t)node * H_DIM + lane]);
    float acc1 = 0.f;
    int j = s0;
    for (; j + 1 < s1; j += 2) {
        int2 e0 = csr2[j], e1 = csr2[j + 1];
        acc0 += __int_as_float(e0.y) * b2f(h[(size_t)e0.x * H_DIM + lane]);
        acc1 += __int_as_float(e1.y) * b2f(h[(size_t)e1.x * H_DIM + lane]);
    }
    if (j < s1) {
        int2 e0 = csr2[j];
        acc0 += __int_as_float(e0.y) * b2f(h[(size_t)e0.x * H_DIM + lane]);
    }
    float v = dn * (acc0 + acc1) + b3[lane];
    feat[(size_t)node * H_DIM + lane]  = v;
    featb[(size_t)node * H_DIM + lane] = f2b(v);
}

// ---------------- heads: y = A*feat (no bias); attr=y@Wa+ba (log-softmax), att=y@Wk+bk ----
// Dual-head shuffle GEMM against packed Wh[64][32]; lanes 0-15 -> lsm, 16-31 -> att.
__global__ __launch_bounds__(256) void head_kernel(const bf16* __restrict__ featb,
                                                   const int* __restrict__ rowstart,
                                                   const int2* __restrict__ csr2,
                                                   const float* __restrict__ dinv,
                                                   const float* __restrict__ Wh,
                                                   const float* __restrict__ ba,
                                                   const float* __restrict__ bk,
                                                   float* __restrict__ lsm,
                                                   float* __restrict__ att) {
    int lane = threadIdx.x & 63;
    int node = blockIdx.x * 4 + __builtin_amdgcn_readfirstlane(threadIdx.x >> 6);
    float dn = dinv[node];
    int s0 = rowstart[node], s1 = rowstart[node + 1];
    float acc0 = dn * b2f(featb[(size_t)node * H_DIM + lane]);
    float acc1 = 0.f;
    int j = s0;
    for (; j + 1 < s1; j += 2) {
        int2 e0 = csr2[j], e1 = csr2[j + 1];
        acc0 += __int_as_float(e0.y) * b2f(featb[(size_t)e0.x * H_DIM + lane]);
        acc1 += __int_as_float(e1.y) * b2f(featb[(size_t)e1.x * H_DIM + lane]);
    }
    if (j < s1) {
        int2 e0 = csr2[j];
        acc0 += __int_as_float(e0.y) * b2f(featb[(size_t)e0.x * H_DIM + lane]);
    }
    float y = dn * (acc0 + acc1);     // no bias on y

    // partial[l] = sum_{i=0..31} y[fbase+i] * Wh[fbase+i][c32]
    int c32 = lane & 31;
    int fbase = lane & 32;
    float part = 0.f;
#pragma unroll
    for (int i = 0; i < 32; i++) {
        float yf = __shfl(y, fbase + i, 64);
        part += yf * Wh[(fbase + i) * 32 + c32];
    }
    float full = part + __shfl(part, lane ^ 32, 64);   // valid for lanes 0..31
    if (lane < 32) {
        float bias = (lane < C_DIM) ? ba[lane] : bk[lane - C_DIM];
        float hv = full + bias;
        if (lane < C_DIM) {
            float m = hv;
#pragma unroll
            for (int off = 1; off < 16; off <<= 1) m = fmaxf(m, __shfl_xor(m, off, 64));
            float e = __expf(hv - m);
            float sum = e;
#pragma unroll
            for (int off = 1; off < 16; off <<= 1) sum += __shfl_xor(sum, off, 64);
            lsm[(size_t)node * C_DIM + lane] = (hv - m) - __logf(sum);
        } else {
            att[(size_t)node * C_DIM + (lane - C_DIM)] = hv;
        }
    }
}

// ---------------- edge dot on bf16 feat ----------------
__global__ __launch_bounds__(256) void edge_dot_kernel(const int* __restrict__ pos,
                                                       const int* __restrict__ neg,
                                                       const bf16* __restrict__ xb,
                                                       float* __restrict__ res) {
    int e = blockIdx.x * 16 + (threadIdx.x >> 4);
    int lane = threadIdx.x & 15;
    int a, b;
    if (e < PE_CNT) {
        a = pos[e];
        b = pos[PE_CNT + e];
    } else {
        int e2 = e - PE_CNT;
        a = neg[e2];
        b = neg[PE_CNT + e2];
    }
    uint2 ua = ((const uint2*)(xb + (size_t)a * H_DIM))[lane];
    uint2 ub = ((const uint2*)(xb + (size_t)b * H_DIM))[lane];
    float a0 = __uint_as_float(ua.x << 16), a1 = __uint_as_float(ua.x & 0xffff0000u);
    float a2 = __uint_as_float(ua.y << 16), a3 = __uint_as_float(ua.y & 0xffff0000u);
    float b0 = __uint_as_float(ub.x << 16), b1 = __uint_as_float(ub.x & 0xffff0000u);
    float b2 = __uint_as_float(ub.y << 16), b3 = __uint_as_float(ub.y & 0xffff0000u);
    float acc = a0 * b0 + a1 * b1 + a2 * b2 + a3 * b3;
#pragma unroll
    for (int off = 1; off < 16; off <<= 1) acc += __shfl_xor(acc, off, 64);
    if (lane == 0) res[e] = acc;
}

// ---------------- launch ----------------

extern "C" void kernel_launch(void* const* d_in, const int* in_sizes, int n_in,
                              void* d_out, int out_size, void* d_ws, size_t ws_size,
                              hipStream_t stream) {
    const float* input = (const float*)d_in[0];
    // d_in[1] = glove = identity: x @ glove == x, skipped exactly.
    const float* W1 = (const float*)d_in[2];
    const float* b1 = (const float*)d_in[3];
    const float* W2 = (const float*)d_in[4];
    const float* b2 = (const float*)d_in[5];
    const float* W3 = (const float*)d_in[6];
    const float* b3 = (const float*)d_in[7];
    const float* Wa = (const float*)d_in[8];
    const float* ba = (const float*)d_in[9];
    const float* Wk = (const float*)d_in[10];
    const float* bk = (const float*)d_in[11];
    const int* ei  = (const int*)d_in[12];
    const int* pos = (const int*)d_in[13];
    const int* neg = (const int*)d_in[14];

    char* ws = (char*)d_ws;
    int*   hist     = (int*)(ws + 0);                 // 200000
    int*   rowstart = (int*)(ws + 200704);            // 200004
    int*   cursor   = (int*)(ws + 401408);            // 200000
    float* dinv     = (float*)(ws + 602112);          // 200000
    int*   partials = (int*)(ws + 802816);            // 256
    float* Wh       = (float*)(ws + 803072);          // 8192
    int2*  csr2     = (int2*)(ws + 811264);           // 6.4 MB
    bf16*  bufA     = (bf16*)(ws + 7211264ULL);       // 6.4 MB
    bf16*  bufB     = (bf16*)(ws + 13611264ULL);      // 6.4 MB (end ~20 MB)

    float* out  = (float*)d_out;
    float* res  = out;                  // 400000
    float* lsm  = out + 400000;         // 800000
    float* att  = out + 1200000;        // 800000
    float* feat = out + 2000000;        // 3200000

    // CSR build (+ Wh pack piggybacked on block 0 of hist)
    hipMemsetAsync(hist, 0, N_NODES * sizeof(int), stream);
    hist_build_kernel<<<(N_EDGES + 255) / 256, 256, 0, stream>>>(ei + N_EDGES, hist, Wa, Wk, Wh);
    scan_block_kernel<<<49, 1024, 0, stream>>>(hist, rowstart, partials);
    scan_partials_kernel<<<1, 64, 0, stream>>>(partials);
    scan_add_kernel<<<196, 256, 0, stream>>>(rowstart, partials, cursor, hist, dinv);
    scatter_kernel<<<(N_EDGES + 255) / 256, 256, 0, stream>>>(ei, cursor, dinv, csr2);

    // layer 1 GEMM (f32 in, bf16 out), LDS-tiled
    gemm_k256_kernel<<<(N_NODES + G_ROWS - 1) / G_ROWS, 256, 0, stream>>>(input, W1, bufA);
    // layer 1 agg (+b1, relu) fused with layer-2 GEMM
    agg_gemm_kernel<1><<<12500, 256, 0, stream>>>(bufA, rowstart, csr2, dinv, b1, W2, bufB);
    // layer 2 agg (+b2) fused with layer-3 GEMM
    agg_gemm_kernel<0><<<12500, 256, 0, stream>>>(bufB, rowstart, csr2, dinv, b2, W3, bufA);
    // layer 3 agg (+b3) -> feat (f32) + featb (bf16)
    agg_out_kernel<<<12500, 256, 0, stream>>>(bufA, rowstart, csr2, dinv, b3, feat, bufB);
    // heads: y = A*feat; attr=y@Wa+ba (log-softmax) ; att=y@Wk+bk
    head_kernel<<<12500, 256, 0, stream>>>(bufB, rowstart, csr2, dinv, Wh, ba, bk, lsm, att);
    // edge dot on bf16 feat
    edge_dot_kernel<<<25000, 256, 0, stream>>>(pos, neg, bufB, res);
}